// Round 1
// 310.842 us; speedup vs baseline: 1.0641x; 1.0641x over previous
//
#include <hip/hip_runtime.h>

// Tucker conv, 2-kernel MFMA pipeline, v2: barrier-free direct-fragment loads.
//   stageA: x[b,c,h,w] -> x1p[b,h',w',s]  — B-frags built from 8 c-strided
//           global fp32 loads per k-chunk (no LDS, no barriers).
//   fusedBC: per (b,h): B-frags read directly from x1p (16B contiguous,
//           L2/L3-hot), 9-offset core GEMM, wave-local LDS transpose (9 KB),
//           expand GEMM + bias -> out. No block-wide barriers.

typedef __attribute__((ext_vector_type(8))) short short8;
typedef __attribute__((ext_vector_type(4))) short short4v;
typedef __attribute__((ext_vector_type(4))) float f32x4;

#define B_    32
#define CIN_  256
#define H_    56
#define W_    56
#define HW_   (H_*W_)          // 3136
#define COUT_ 256
#define HP_   58
#define WP_   64

// workspace byte offsets (16B-aligned)
#define OFF_FIRSTW  0u                        // bf16 [64][256]        32768 B
#define OFF_COREW   32768u                    // bf16 [9][64][64]      73728 B
#define OFF_LASTW   106496u                   // bf16 [256][64]        32768 B
#define OFF_X1P     139264u                   // bf16 [32][58][64][64] 15204352 B (+slack)

__device__ __forceinline__ unsigned short f2bf(float f) {
  union { float f; unsigned int u; } v; v.f = f;
  return (unsigned short)((v.u + 0x7FFFu + ((v.u >> 16) & 1u)) >> 16);
}
__device__ __forceinline__ short4v pack4(f32x4 a) {
  short4v p;
  p.x = (short)f2bf(a.x); p.y = (short)f2bf(a.y);
  p.z = (short)f2bf(a.z); p.w = (short)f2bf(a.w);
  return p;
}

// ---- prep: cast/transpose small factors to bf16 ----
__global__ __launch_bounds__(256) void prep_kernel(
    const float* __restrict__ first,   // [64][256]
    const float* __restrict__ core,    // [64][64][3][3]
    const float* __restrict__ last,    // [256][64]
    unsigned short* __restrict__ ws16) {
  int i = blockIdx.x * 256 + threadIdx.x;   // 69632 threads
  if (i < 16384) {
    ws16[(OFF_FIRSTW >> 1) + i] = f2bf(first[i]);                 // [s][c]
  } else if (i < 53248) {
    int j = i - 16384;                                            // coreW[t][r][s]
    int t = j >> 12, r = (j >> 6) & 63, s = j & 63;
    ws16[(OFF_COREW >> 1) + j] = f2bf(core[(r * 64 + s) * 9 + t]);
  } else {
    ws16[(OFF_LASTW >> 1) + (i - 53248)] = f2bf(last[i - 53248]); // [o][r]
  }
}

// ---- stage A: one block per (b, h'); LDS-free, barrier-free.
//      Wave covers 16 w' columns x all 64 s. B-frag = 8 c-strided fp32 loads
//      (per instr: 4 c-rows x 64 contiguous bytes -> coalesced), cvt in-reg.
__global__ __launch_bounds__(256, 6) void stageA_kernel(
    const float* __restrict__ x,
    unsigned short* __restrict__ ws16) {
  const unsigned short* firstW = ws16 + (OFF_FIRSTW >> 1);
  unsigned short* x1p = ws16 + (OFF_X1P >> 1);

  int tid = threadIdx.x, wave = tid >> 6, lane = tid & 63;
  int quad = lane >> 4, l15 = lane & 15;
  int bid0 = blockIdx.x;                 // 1856 = 8*232
  int bid = (bid0 & 7) * 232 + (bid0 >> 3);   // XCD-contiguous swizzle
  int b = bid / HP_, hp = bid - b * HP_;
  size_t rowbase = (size_t)(b * HP_ + hp) * (WP_ * 64);

  if (hp == 0 || hp == HP_ - 1) {       // halo rows: true zeros
    short8 z = {0,0,0,0,0,0,0,0};
#pragma unroll
    for (int i = 0; i < 2; ++i)
      *(short8*)(x1p + rowbase + (size_t)(tid + i * 256) * 8) = z;
    return;
  }

  int h = hp - 1;
  int wp = wave * 16 + l15;             // w' column this lane produces: 0..63
  bool valid = (wp >= 1 && wp <= 56);   // w'=0 and 57..63 are halo zeros
  int wsrc = valid ? (wp - 1) : 0;      // clamp keeps loads in-bounds
  const float* xcol = x + (size_t)b * (CIN_ * HW_) + h * W_ + wsrc;

  f32x4 acc[4] = {{0,0,0,0},{0,0,0,0},{0,0,0,0},{0,0,0,0}};
#pragma unroll 2
  for (int c0 = 0; c0 < CIN_; c0 += 32) {
    const float* p = xcol + (size_t)(c0 + quad * 8) * HW_;
    float xv[8];
#pragma unroll
    for (int j = 0; j < 8; ++j) xv[j] = p[(size_t)j * HW_];
    short8 bfrag;
#pragma unroll
    for (int j = 0; j < 8; ++j) bfrag[j] = (short)f2bf(xv[j]);
#pragma unroll
    for (int mt = 0; mt < 4; ++mt) {
      short8 af = *(const short8*)(firstW + (mt * 16 + l15) * CIN_ + c0 + quad * 8);
      acc[mt] = __builtin_amdgcn_mfma_f32_16x16x32_bf16(af, bfrag, acc[mt], 0, 0, 0);
    }
  }
  // store: x1p[b,hp,w',s]; s = mt*16 + quad*4 + reg; invalid lanes write zeros
  short4v zero4 = {0,0,0,0};
#pragma unroll
  for (int mt = 0; mt < 4; ++mt) {
    short4v r = valid ? pack4(acc[mt]) : zero4;
    *(short4v*)(x1p + rowbase + (size_t)wp * 64 + mt * 16 + quad * 4) = r;
  }
}

// ---- fused B+C: one block per (b, h); no staging, no block barriers ----
#define XTS 72            // yt halfs per w-entry (64 r + 8 pad)
__global__ __launch_bounds__(256, 4) void fusedBC_kernel(
    const unsigned short* __restrict__ ws16,
    const float* __restrict__ bias,
    float* __restrict__ out) {
  __shared__ unsigned short yt[64 * XTS];   // 9216 B, wave-local transpose only
  const unsigned short* coreW = ws16 + (OFF_COREW >> 1);
  const unsigned short* lastW = ws16 + (OFF_LASTW >> 1);
  const unsigned short* x1p   = ws16 + (OFF_X1P >> 1);

  int tid = threadIdx.x, wave = tid >> 6, lane = tid & 63;
  int quad = lane >> 4, l15 = lane & 15;
  int bid0 = blockIdx.x;                 // 1792 = 8*224
  int bid = (bid0 & 7) * 224 + (bid0 >> 3);   // XCD-contiguous: h-neighbors share L2
  int b = bid / H_, h = bid - b * H_;
  int w = wave * 16 + l15;              // 0..63 (w>=56 garbage, masked at store)

  // per-lane base into x1p for B-frags: rows h..h+2, col w+kw, 16B contiguous k
  const unsigned short* xw = x1p + (size_t)(b * HP_ + h) * (WP_ * 64)
                             + (size_t)w * 64 + quad * 8;

  // ---- B-phase: y1[r=64][w] = sum_{t,s} core * x1; B-frags direct from global
  f32x4 acc[4] = {{0,0,0,0},{0,0,0,0},{0,0,0,0},{0,0,0,0}};
#pragma unroll
  for (int kh = 0; kh < 3; ++kh) {
#pragma unroll
    for (int kw = 0; kw < 3; ++kw) {
      int t = kh * 3 + kw;
#pragma unroll
      for (int k0 = 0; k0 < 64; k0 += 32) {
        short8 bfrag = *(const short8*)(xw + (size_t)(kh * WP_ + kw) * 64 + k0);
#pragma unroll
        for (int mt = 0; mt < 4; ++mt) {
          short8 af = *(const short8*)(coreW + (t * 64 + mt * 16 + l15) * 64 + k0 + quad * 8);
          acc[mt] = __builtin_amdgcn_mfma_f32_16x16x32_bf16(af, bfrag, acc[mt], 0, 0, 0);
        }
      }
    }
  }

  // ---- wave-local transpose through LDS: yt[w][r] (each wave touches only
  //      its own w-columns -> no barrier needed; lgkmcnt ordering suffices)
#pragma unroll
  for (int mt = 0; mt < 4; ++mt)
    *(short4v*)&yt[w * XTS + mt * 16 + quad * 4] = pack4(acc[mt]);

  // ---- C-phase: out[o=256][w] = bias + last @ y1
  f32x4 acc2[16];
#pragma unroll
  for (int mt = 0; mt < 16; ++mt) acc2[mt] = (f32x4){0, 0, 0, 0};
#pragma unroll
  for (int k0 = 0; k0 < 64; k0 += 32) {
    short8 bfrag = *(const short8*)&yt[w * XTS + k0 + quad * 8];
#pragma unroll
    for (int mt = 0; mt < 16; ++mt) {
      short8 af = *(const short8*)(lastW + (mt * 16 + l15) * 64 + k0 + quad * 8);
      acc2[mt] = __builtin_amdgcn_mfma_f32_16x16x32_bf16(af, bfrag, acc2[mt], 0, 0, 0);
    }
  }

  if (w < W_) {
    float* ob = out + (size_t)b * (COUT_ * HW_) + h * W_ + w;
#pragma unroll
    for (int mt = 0; mt < 16; ++mt) {
      float4 bv = *(const float4*)(bias + mt * 16 + quad * 4);
      int o = mt * 16 + quad * 4;
      ob[(size_t)(o + 0) * HW_] = acc2[mt].x + bv.x;
      ob[(size_t)(o + 1) * HW_] = acc2[mt].y + bv.y;
      ob[(size_t)(o + 2) * HW_] = acc2[mt].z + bv.z;
      ob[(size_t)(o + 3) * HW_] = acc2[mt].w + bv.w;
    }
  }
}

extern "C" void kernel_launch(void* const* d_in, const int* in_sizes, int n_in,
                              void* d_out, int out_size, void* d_ws, size_t ws_size,
                              hipStream_t stream) {
  const float* x     = (const float*)d_in[0];
  const float* first = (const float*)d_in[1];
  const float* core  = (const float*)d_in[2];
  const float* last  = (const float*)d_in[3];
  const float* bias  = (const float*)d_in[4];
  float* out = (float*)d_out;
  unsigned short* ws16 = (unsigned short*)d_ws;

  prep_kernel<<<272, 256, 0, stream>>>(first, core, last, ws16);
  stageA_kernel<<<B_ * HP_, 256, 0, stream>>>(x, ws16);
  fusedBC_kernel<<<B_ * H_, 256, 0, stream>>>(ws16, bias, out);
}

// Round 3
// 303.476 us; speedup vs baseline: 1.0899x; 1.0243x over previous
//
#include <hip/hip_runtime.h>

// Tucker conv, 2-kernel MFMA pipeline, v3 (resubmit — round-2 bench was an
// infra failure, no kernel verdict):
//   stageA: software-pipelined strided x loads (2-deep), MFMA, wave-local LDS
//           transpose -> fully coalesced 1KB x1p stores.
//   fusedBC: explicit t+1 prefetch of x1p B-frags; C-phase STREAMED in 4
//           o-groups (live acc = 16 regs, was 64) to lift occupancy.

typedef __attribute__((ext_vector_type(8))) short short8;
typedef __attribute__((ext_vector_type(4))) short short4v;
typedef __attribute__((ext_vector_type(4))) float f32x4;

#define B_    32
#define CIN_  256
#define H_    56
#define W_    56
#define HW_   (H_*W_)          // 3136
#define COUT_ 256
#define HP_   58
#define WP_   64

// workspace byte offsets (16B-aligned)
#define OFF_FIRSTW  0u                        // bf16 [64][256]        32768 B
#define OFF_COREW   32768u                    // bf16 [9][64][64]      73728 B
#define OFF_LASTW   106496u                   // bf16 [256][64]        32768 B
#define OFF_X1P     139264u                   // bf16 [32][58][64][64] 15204352 B (+slack)

__device__ __forceinline__ unsigned short f2bf(float f) {
  union { float f; unsigned int u; } v; v.f = f;
  return (unsigned short)((v.u + 0x7FFFu + ((v.u >> 16) & 1u)) >> 16);
}
__device__ __forceinline__ short4v pack4(f32x4 a) {
  short4v p;
  p.x = (short)f2bf(a.x); p.y = (short)f2bf(a.y);
  p.z = (short)f2bf(a.z); p.w = (short)f2bf(a.w);
  return p;
}

// ---- prep: cast/transpose small factors to bf16 ----
__global__ __launch_bounds__(256) void prep_kernel(
    const float* __restrict__ first,   // [64][256]
    const float* __restrict__ core,    // [64][64][3][3]
    const float* __restrict__ last,    // [256][64]
    unsigned short* __restrict__ ws16) {
  int i = blockIdx.x * 256 + threadIdx.x;   // 69632 threads
  if (i < 16384) {
    ws16[(OFF_FIRSTW >> 1) + i] = f2bf(first[i]);                 // [s][c]
  } else if (i < 53248) {
    int j = i - 16384;                                            // coreW[t][r][s]
    int t = j >> 12, r = (j >> 6) & 63, s = j & 63;
    ws16[(OFF_COREW >> 1) + j] = f2bf(core[(r * 64 + s) * 9 + t]);
  } else {
    ws16[(OFF_LASTW >> 1) + (i - 53248)] = f2bf(last[i - 53248]); // [o][r]
  }
}

// ---- stage A: one block per (b, h'); pipelined strided loads, MFMA,
//      wave-local LDS transpose -> coalesced x1p stores.
#define SATS 72   // LDS halfs per wp-entry (64 s + 8 pad)
__global__ __launch_bounds__(256, 6) void stageA_kernel(
    const float* __restrict__ x,
    unsigned short* __restrict__ ws16) {
  __shared__ unsigned short st[4][16][SATS];   // 9216 B, wave-local
  const unsigned short* firstW = ws16 + (OFF_FIRSTW >> 1);
  unsigned short* x1p = ws16 + (OFF_X1P >> 1);

  int tid = threadIdx.x, wave = tid >> 6, lane = tid & 63;
  int quad = lane >> 4, l15 = lane & 15;
  int bid0 = blockIdx.x;                 // 1856 = 8*232
  int bid = (bid0 & 7) * 232 + (bid0 >> 3);   // XCD-contiguous swizzle
  int b = bid / HP_, hp = bid - b * HP_;
  size_t rowbase = (size_t)(b * HP_ + hp) * (WP_ * 64);

  if (hp == 0 || hp == HP_ - 1) {       // halo rows: true zeros
    short8 z = {0,0,0,0,0,0,0,0};
#pragma unroll
    for (int i = 0; i < 2; ++i)
      *(short8*)(x1p + rowbase + (size_t)(tid + i * 256) * 8) = z;
    return;
  }

  int h = hp - 1;
  int wp = wave * 16 + l15;             // w' column this lane produces: 0..63
  bool valid = (wp >= 1 && wp <= 56);   // w'=0 and 57..63 are halo zeros
  int wsrc = valid ? (wp - 1) : 0;      // clamp keeps loads in-bounds
  const float* xcol = x + (size_t)b * (CIN_ * HW_) + h * W_ + wsrc;

  f32x4 acc[4] = {{0,0,0,0},{0,0,0,0},{0,0,0,0},{0,0,0,0}};
  float xv[2][8];
#pragma unroll
  for (int j = 0; j < 8; ++j) xv[0][j] = xcol[(size_t)(quad * 8 + j) * HW_];

#pragma unroll
  for (int cc = 0; cc < 8; ++cc) {       // fully unrolled: indices static
    int cur = cc & 1;
    if (cc < 7) {                        // issue next chunk's loads first
      const float* p = xcol + (size_t)((cc + 1) * 32 + quad * 8) * HW_;
#pragma unroll
      for (int j = 0; j < 8; ++j) xv[cur ^ 1][j] = p[(size_t)j * HW_];
    }
    short8 bfrag;
#pragma unroll
    for (int j = 0; j < 8; ++j) bfrag[j] = (short)f2bf(xv[cur][j]);
#pragma unroll
    for (int mt = 0; mt < 4; ++mt) {
      short8 af = *(const short8*)(firstW + (mt * 16 + l15) * CIN_ + cc * 32 + quad * 8);
      acc[mt] = __builtin_amdgcn_mfma_f32_16x16x32_bf16(af, bfrag, acc[mt], 0, 0, 0);
    }
  }

  // wave-local transpose: st[wave][wp_local][s]; invalid lanes deposit zeros
  short4v zero4 = {0,0,0,0};
#pragma unroll
  for (int mt = 0; mt < 4; ++mt) {
    short4v r = valid ? pack4(acc[mt]) : zero4;
    *(short4v*)&st[wave][l15][mt * 16 + quad * 4] = r;
  }
  // readback linear, store coalesced (1KB contiguous per instruction)
#pragma unroll
  for (int i = 0; i < 2; ++i) {
    int idx = i * 512 + lane * 8;        // half-index within wave's 16x64 tile
    int r = idx >> 6, s0 = idx & 63;
    short8 v = *(const short8*)&st[wave][r][s0];
    *(short8*)(x1p + rowbase + (size_t)wave * 1024 + idx) = v;
  }
}

// ---- fused B+C: one block per (b, h); prefetched B-frags, streamed C ----
#define XTS 72            // yt halfs per w-entry (64 r + 8 pad)
__global__ __launch_bounds__(256, 5) void fusedBC_kernel(
    const unsigned short* __restrict__ ws16,
    const float* __restrict__ bias,
    float* __restrict__ out) {
  __shared__ unsigned short yt[64 * XTS];   // 9216 B, wave-local transpose only
  const unsigned short* coreW = ws16 + (OFF_COREW >> 1);
  const unsigned short* lastW = ws16 + (OFF_LASTW >> 1);
  const unsigned short* x1p   = ws16 + (OFF_X1P >> 1);

  int tid = threadIdx.x, wave = tid >> 6, lane = tid & 63;
  int quad = lane >> 4, l15 = lane & 15;
  int bid0 = blockIdx.x;                 // 1792 = 8*224
  int bid = (bid0 & 7) * 224 + (bid0 >> 3);   // XCD-contiguous: h-neighbors share L2
  int b = bid / H_, h = bid - b * H_;
  int w = wave * 16 + l15;              // 0..63 (w>=56 garbage, masked at store)

  // per-lane base into x1p for B-frags: rows h..h+2, col w+kw, 16B contiguous k
  const unsigned short* xw = x1p + (size_t)(b * HP_ + h) * (WP_ * 64)
                             + (size_t)w * 64 + quad * 8;

  // ---- B-phase: y1[r=64][w] = sum_{t,s} core * x1; prefetch t+1 frags
  f32x4 acc[4] = {{0,0,0,0},{0,0,0,0},{0,0,0,0},{0,0,0,0}};
  short8 bc0 = *(const short8*)(xw);
  short8 bc1 = *(const short8*)(xw + 32);
#pragma unroll
  for (int t = 0; t < 9; ++t) {
    short8 bn0, bn1;
    if (t < 8) {
      int kh2 = (t + 1) / 3, kw2 = (t + 1) - kh2 * 3;
      const unsigned short* p = xw + (size_t)(kh2 * WP_ + kw2) * 64;
      bn0 = *(const short8*)p;
      bn1 = *(const short8*)(p + 32);
    }
#pragma unroll
    for (int mt = 0; mt < 4; ++mt) {
      short8 af = *(const short8*)(coreW + (t * 64 + mt * 16 + l15) * 64 + quad * 8);
      acc[mt] = __builtin_amdgcn_mfma_f32_16x16x32_bf16(af, bc0, acc[mt], 0, 0, 0);
    }
#pragma unroll
    for (int mt = 0; mt < 4; ++mt) {
      short8 af = *(const short8*)(coreW + (t * 64 + mt * 16 + l15) * 64 + 32 + quad * 8);
      acc[mt] = __builtin_amdgcn_mfma_f32_16x16x32_bf16(af, bc1, acc[mt], 0, 0, 0);
    }
    if (t < 8) { bc0 = bn0; bc1 = bn1; }
  }

  // ---- wave-local transpose through LDS: yt[w][r] (each wave touches only
  //      its own w-columns -> no barrier needed)
#pragma unroll
  for (int mt = 0; mt < 4; ++mt)
    *(short4v*)&yt[w * XTS + mt * 16 + quad * 4] = pack4(acc[mt]);

  // ---- C-phase, streamed: out[o-group of 64][w], 4 groups, live acc = 16 regs
  float* ob = out + (size_t)b * (COUT_ * HW_) + h * W_ + w;
#pragma unroll
  for (int g = 0; g < 4; ++g) {
    f32x4 a2[4] = {{0,0,0,0},{0,0,0,0},{0,0,0,0},{0,0,0,0}};
#pragma unroll
    for (int k0 = 0; k0 < 64; k0 += 32) {
      short8 bfrag = *(const short8*)&yt[w * XTS + k0 + quad * 8];
#pragma unroll
      for (int m = 0; m < 4; ++m) {
        short8 af = *(const short8*)(lastW + (g * 64 + m * 16 + l15) * 64 + k0 + quad * 8);
        a2[m] = __builtin_amdgcn_mfma_f32_16x16x32_bf16(af, bfrag, a2[m], 0, 0, 0);
      }
    }
    if (w < W_) {
#pragma unroll
      for (int m = 0; m < 4; ++m) {
        int o = g * 64 + m * 16 + quad * 4;
        float4 bv = *(const float4*)(bias + o);
        ob[(size_t)(o + 0) * HW_] = a2[m].x + bv.x;
        ob[(size_t)(o + 1) * HW_] = a2[m].y + bv.y;
        ob[(size_t)(o + 2) * HW_] = a2[m].z + bv.z;
        ob[(size_t)(o + 3) * HW_] = a2[m].w + bv.w;
      }
    }
  }
}

extern "C" void kernel_launch(void* const* d_in, const int* in_sizes, int n_in,
                              void* d_out, int out_size, void* d_ws, size_t ws_size,
                              hipStream_t stream) {
  const float* x     = (const float*)d_in[0];
  const float* first = (const float*)d_in[1];
  const float* core  = (const float*)d_in[2];
  const float* last  = (const float*)d_in[3];
  const float* bias  = (const float*)d_in[4];
  float* out = (float*)d_out;
  unsigned short* ws16 = (unsigned short*)d_ws;

  prep_kernel<<<272, 256, 0, stream>>>(first, core, last, ws16);
  stageA_kernel<<<B_ * HP_, 256, 0, stream>>>(x, ws16);
  fusedBC_kernel<<<B_ * H_, 256, 0, stream>>>(ws16, bias, out);
}

// Round 4
// 297.721 us; speedup vs baseline: 1.1110x; 1.0193x over previous
//
#include <hip/hip_runtime.h>

// Tucker conv, 2-kernel MFMA pipeline, v4:
//   stageA: UNCHANGED from v3 (clean A/B isolation).
//   fusedBC: REWRITTEN — 256 blocks (1/CU), each owns (b, 7 h-rows); coreW+
//     lastW staged in LDS ONCE per block (padded stride 72 halfs -> ~2-way
//     banks on ds_read_b128), rows loop reads factors from LDS instead of
//     re-streaming 104 KB/wave from L2. Per-wave VMEM drops ~5.6x.

typedef __attribute__((ext_vector_type(8))) short short8;
typedef __attribute__((ext_vector_type(4))) short short4v;
typedef __attribute__((ext_vector_type(4))) float f32x4;

#define B_    32
#define CIN_  256
#define H_    56
#define W_    56
#define HW_   (H_*W_)          // 3136
#define COUT_ 256
#define HP_   58
#define WP_   64

// workspace byte offsets (16B-aligned)
#define OFF_FIRSTW  0u                        // bf16 [64][256]        32768 B
#define OFF_COREW   32768u                    // bf16 [9][64][64]      73728 B
#define OFF_LASTW   106496u                   // bf16 [256][64]        32768 B
#define OFF_X1P     139264u                   // bf16 [32][58][64][64] 15204352 B (+slack)

__device__ __forceinline__ unsigned short f2bf(float f) {
  union { float f; unsigned int u; } v; v.f = f;
  return (unsigned short)((v.u + 0x7FFFu + ((v.u >> 16) & 1u)) >> 16);
}
__device__ __forceinline__ short4v pack4(f32x4 a) {
  short4v p;
  p.x = (short)f2bf(a.x); p.y = (short)f2bf(a.y);
  p.z = (short)f2bf(a.z); p.w = (short)f2bf(a.w);
  return p;
}

// ---- prep: cast/transpose small factors to bf16 ----
__global__ __launch_bounds__(256) void prep_kernel(
    const float* __restrict__ first,   // [64][256]
    const float* __restrict__ core,    // [64][64][3][3]
    const float* __restrict__ last,    // [256][64]
    unsigned short* __restrict__ ws16) {
  int i = blockIdx.x * 256 + threadIdx.x;   // 69632 threads
  if (i < 16384) {
    ws16[(OFF_FIRSTW >> 1) + i] = f2bf(first[i]);                 // [s][c]
  } else if (i < 53248) {
    int j = i - 16384;                                            // coreW[t][r][s]
    int t = j >> 12, r = (j >> 6) & 63, s = j & 63;
    ws16[(OFF_COREW >> 1) + j] = f2bf(core[(r * 64 + s) * 9 + t]);
  } else {
    ws16[(OFF_LASTW >> 1) + (i - 53248)] = f2bf(last[i - 53248]); // [o][r]
  }
}

// ---- stage A: one block per (b, h'); pipelined strided loads, MFMA,
//      wave-local LDS transpose -> coalesced x1p stores. (unchanged v3)
#define SATS 72   // LDS halfs per wp-entry (64 s + 8 pad)
__global__ __launch_bounds__(256, 6) void stageA_kernel(
    const float* __restrict__ x,
    unsigned short* __restrict__ ws16) {
  __shared__ unsigned short st[4][16][SATS];   // 9216 B, wave-local
  const unsigned short* firstW = ws16 + (OFF_FIRSTW >> 1);
  unsigned short* x1p = ws16 + (OFF_X1P >> 1);

  int tid = threadIdx.x, wave = tid >> 6, lane = tid & 63;
  int quad = lane >> 4, l15 = lane & 15;
  int bid0 = blockIdx.x;                 // 1856 = 8*232
  int bid = (bid0 & 7) * 232 + (bid0 >> 3);   // XCD-contiguous swizzle
  int b = bid / HP_, hp = bid - b * HP_;
  size_t rowbase = (size_t)(b * HP_ + hp) * (WP_ * 64);

  if (hp == 0 || hp == HP_ - 1) {       // halo rows: true zeros
    short8 z = {0,0,0,0,0,0,0,0};
#pragma unroll
    for (int i = 0; i < 2; ++i)
      *(short8*)(x1p + rowbase + (size_t)(tid + i * 256) * 8) = z;
    return;
  }

  int h = hp - 1;
  int wp = wave * 16 + l15;             // w' column this lane produces: 0..63
  bool valid = (wp >= 1 && wp <= 56);   // w'=0 and 57..63 are halo zeros
  int wsrc = valid ? (wp - 1) : 0;      // clamp keeps loads in-bounds
  const float* xcol = x + (size_t)b * (CIN_ * HW_) + h * W_ + wsrc;

  f32x4 acc[4] = {{0,0,0,0},{0,0,0,0},{0,0,0,0},{0,0,0,0}};
  float xv[2][8];
#pragma unroll
  for (int j = 0; j < 8; ++j) xv[0][j] = xcol[(size_t)(quad * 8 + j) * HW_];

#pragma unroll
  for (int cc = 0; cc < 8; ++cc) {       // fully unrolled: indices static
    int cur = cc & 1;
    if (cc < 7) {                        // issue next chunk's loads first
      const float* p = xcol + (size_t)((cc + 1) * 32 + quad * 8) * HW_;
#pragma unroll
      for (int j = 0; j < 8; ++j) xv[cur ^ 1][j] = p[(size_t)j * HW_];
    }
    short8 bfrag;
#pragma unroll
    for (int j = 0; j < 8; ++j) bfrag[j] = (short)f2bf(xv[cur][j]);
#pragma unroll
    for (int mt = 0; mt < 4; ++mt) {
      short8 af = *(const short8*)(firstW + (mt * 16 + l15) * CIN_ + cc * 32 + quad * 8);
      acc[mt] = __builtin_amdgcn_mfma_f32_16x16x32_bf16(af, bfrag, acc[mt], 0, 0, 0);
    }
  }

  // wave-local transpose: st[wave][wp_local][s]; invalid lanes deposit zeros
  short4v zero4 = {0,0,0,0};
#pragma unroll
  for (int mt = 0; mt < 4; ++mt) {
    short4v r = valid ? pack4(acc[mt]) : zero4;
    *(short4v*)&st[wave][l15][mt * 16 + quad * 4] = r;
  }
  // readback linear, store coalesced (1KB contiguous per instruction)
#pragma unroll
  for (int i = 0; i < 2; ++i) {
    int idx = i * 512 + lane * 8;        // half-index within wave's 16x64 tile
    int r = idx >> 6, s0 = idx & 63;
    short8 v = *(const short8*)&st[wave][r][s0];
    *(short8*)(x1p + rowbase + (size_t)wave * 1024 + idx) = v;
  }
}

// ---- fused B+C v4: 256 blocks; block = (b, 7-row h-group); factors in LDS ----
#define CWP 72            // padded row stride (halfs) for cw/lw fragments
#define XTS 72            // yt halfs per w-entry (64 r + 8 pad)
__global__ __launch_bounds__(256, 1) void fusedBC_kernel(
    const unsigned short* __restrict__ ws16,
    const float* __restrict__ bias,
    float* __restrict__ out) {
  __shared__ unsigned short cw[9 * 64 * CWP];   // 82944 B  coreW [t][r][s]
  __shared__ unsigned short lw[256 * CWP];      // 36864 B  lastW [o][r]
  __shared__ unsigned short yt[64 * XTS];       //  9216 B  transpose buf
  const unsigned short* coreW = ws16 + (OFF_COREW >> 1);
  const unsigned short* lastW = ws16 + (OFF_LASTW >> 1);
  const unsigned short* x1p   = ws16 + (OFF_X1P >> 1);

  int tid = threadIdx.x, wave = tid >> 6, lane = tid & 63;
  int quad = lane >> 4, l15 = lane & 15;
  int bid = blockIdx.x;                 // 256 = 32 b * 8 hgroups
  int b = bid >> 3, hg = bid & 7;
  int h0 = hg * 7;                      // rows h0..h0+6 (8*7 = 56 exactly)

  // ---- one-time factor staging into LDS (row stride 64 -> CWP)
  for (int ci = tid; ci < 9 * 64 * 8; ci += 256) {        // coreW: 4608 chunks
    int row = ci >> 3, s0 = (ci & 7) * 8;
    *(short8*)&cw[row * CWP + s0] = *(const short8*)(coreW + row * 64 + s0);
  }
  for (int ci = tid; ci < 256 * 8; ci += 256) {           // lastW: 2048 chunks
    int row = ci >> 3, s0 = (ci & 7) * 8;
    *(short8*)&lw[row * CWP + s0] = *(const short8*)(lastW + row * 64 + s0);
  }
  __syncthreads();

  int w = wave * 16 + l15;              // 0..63 (w>=56 garbage, masked at store)

  for (int hr = 0; hr < 7; ++hr) {
    int h = h0 + hr;
    // per-lane base into x1p: rows h..h+2, col w+kw, 16B contiguous k
    const unsigned short* xw = x1p + (size_t)(b * HP_ + h) * (WP_ * 64)
                               + (size_t)w * 64 + quad * 8;

    // ---- B-phase: y1[r=64][w] = sum_{t,s} core * x1; prefetch t+1 frags
    f32x4 acc[4] = {{0,0,0,0},{0,0,0,0},{0,0,0,0},{0,0,0,0}};
    short8 bc0 = *(const short8*)(xw);
    short8 bc1 = *(const short8*)(xw + 32);
#pragma unroll
    for (int t = 0; t < 9; ++t) {
      short8 bn0, bn1;
      if (t < 8) {
        int kh2 = (t + 1) / 3, kw2 = (t + 1) - kh2 * 3;
        const unsigned short* p = xw + (size_t)(kh2 * WP_ + kw2) * 64;
        bn0 = *(const short8*)p;
        bn1 = *(const short8*)(p + 32);
      }
#pragma unroll
      for (int mt = 0; mt < 4; ++mt) {
        short8 af = *(const short8*)&cw[(t * 64 + mt * 16 + l15) * CWP + quad * 8];
        acc[mt] = __builtin_amdgcn_mfma_f32_16x16x32_bf16(af, bc0, acc[mt], 0, 0, 0);
      }
#pragma unroll
      for (int mt = 0; mt < 4; ++mt) {
        short8 af = *(const short8*)&cw[(t * 64 + mt * 16 + l15) * CWP + 32 + quad * 8];
        acc[mt] = __builtin_amdgcn_mfma_f32_16x16x32_bf16(af, bc1, acc[mt], 0, 0, 0);
      }
      if (t < 8) { bc0 = bn0; bc1 = bn1; }
    }

    // ---- wave-local transpose through LDS: yt[w][r] (same wave writes and
    //      reads only its own w-columns; in-wave LDS ordering suffices, and
    //      WAR across hr iterations is handled by compiler lgkmcnt)
#pragma unroll
    for (int mt = 0; mt < 4; ++mt)
      *(short4v*)&yt[w * XTS + mt * 16 + quad * 4] = pack4(acc[mt]);

    // ---- C-phase, streamed: 4 o-groups of 64, factors from LDS
    float* ob = out + (size_t)b * (COUT_ * HW_) + h * W_ + w;
#pragma unroll
    for (int g = 0; g < 4; ++g) {
      f32x4 a2[4] = {{0,0,0,0},{0,0,0,0},{0,0,0,0},{0,0,0,0}};
#pragma unroll
      for (int k0 = 0; k0 < 64; k0 += 32) {
        short8 bfrag = *(const short8*)&yt[w * XTS + k0 + quad * 8];
#pragma unroll
        for (int m = 0; m < 4; ++m) {
          short8 af = *(const short8*)&lw[(g * 64 + m * 16 + l15) * CWP + k0 + quad * 8];
          a2[m] = __builtin_amdgcn_mfma_f32_16x16x32_bf16(af, bfrag, a2[m], 0, 0, 0);
        }
      }
      if (w < W_) {
#pragma unroll
        for (int m = 0; m < 4; ++m) {
          int o = g * 64 + m * 16 + quad * 4;
          float4 bv = *(const float4*)(bias + o);
          ob[(size_t)(o + 0) * HW_] = a2[m].x + bv.x;
          ob[(size_t)(o + 1) * HW_] = a2[m].y + bv.y;
          ob[(size_t)(o + 2) * HW_] = a2[m].z + bv.z;
          ob[(size_t)(o + 3) * HW_] = a2[m].w + bv.w;
        }
      }
    }
  }
}

extern "C" void kernel_launch(void* const* d_in, const int* in_sizes, int n_in,
                              void* d_out, int out_size, void* d_ws, size_t ws_size,
                              hipStream_t stream) {
  const float* x     = (const float*)d_in[0];
  const float* first = (const float*)d_in[1];
  const float* core  = (const float*)d_in[2];
  const float* last  = (const float*)d_in[3];
  const float* bias  = (const float*)d_in[4];
  float* out = (float*)d_out;
  unsigned short* ws16 = (unsigned short*)d_ws;

  prep_kernel<<<272, 256, 0, stream>>>(first, core, last, ws16);
  stageA_kernel<<<B_ * HP_, 256, 0, stream>>>(x, ws16);
  fusedBC_kernel<<<256, 256, 0, stream>>>(ws16, bias, out);
}